// Round 4
// baseline (9285.208 us; speedup 1.0000x reference)
//
#include <hip/hip_runtime.h>

// ---------------------------------------------------------------------------
// V7: persistent MFMA LSTM — forced load batching + L0/L1 decoupling.
//  Protocol (verified V4-V6): release = write-through h stores (sc0 sc1) ->
//  __syncthreads vmcnt drain -> per-WG relaxed flag store.  acquire = wave-0
//  polls flags -> agent acquire fence (L1/L2 inv) -> __syncthreads -> normal
//  cached loads.
//  NEW vs V6:
//   1. asm volatile("" ::: "memory") between load-issue and consume blocks.
//      V6's VGPR_Count=156 proved the compiler re-sank the staged loads
//      (48 v4u arrays would need ~300 VGPRs) -> refill still ran as dependent
//      chains.  The compiler barrier forces all loads in flight; waitcnt at
//      first use remains partial (vmcnt(N)).
//   2. h1 is TRIPLE-buffered (slot = t%3).  L0's slot-reuse guard relaxes to
//      L1-flags >= i-1 (vs >= i): L0 no longer waits for L1's current
//      iteration (the 24-k-tile longer path) -- steady-state step time = L0's
//      own cycle; L1 chases with ~2 iterations of slack.  L1 waits unchanged.
// ---------------------------------------------------------------------------

constexpr int BB   = 64;
constexpr int TT   = 1024;
constexpr int DIN  = 256;
constexpr int H0   = 512;
constexpr int H1   = 256;
constexpr int NWG0 = 128;
constexpr int NWG1 = 64;
constexpr int NWG  = NWG0 + NWG1;
constexpr int NTHR = 256;
constexpr int NKT  = 24;       // K = 768 = 24 tiles of 32

typedef _Float16 v8h __attribute__((ext_vector_type(8)));
typedef __fp16   v2p __attribute__((ext_vector_type(2)));   // cvt_pkrtz result type
typedef float    v4f __attribute__((ext_vector_type(4)));
typedef unsigned int v4u __attribute__((ext_vector_type(4)));

union U1 { unsigned u; v2p h; };
union U4 { v4u u; v8h h; };

__device__ __forceinline__ unsigned pk2(float a, float b){
  U1 c; c.h = __builtin_amdgcn_cvt_pkrtz(a, b); return c.u;
}
__device__ __forceinline__ float lo16(unsigned u){ U1 c; c.u = u; return (float)c.h[0]; }
__device__ __forceinline__ float hi16(unsigned u){ U1 c; c.u = u; return (float)c.h[1]; }
__device__ __forceinline__ v8h as_h8(v4u u){ U4 c; c.u = u; return c.h; }

__device__ __forceinline__ v4f mfma16(v8h a, v8h b, v4f c){
  return __builtin_amdgcn_mfma_f32_16x16x32_f16(a, b, c, 0, 0, 0);
}

__device__ __forceinline__ float sigf(float v){ return 1.0f / (1.0f + __expf(-v)); }
__device__ __forceinline__ float tanhf_(float v){
  float e = __expf(2.0f * v);
  return 1.0f - 2.0f / (e + 1.0f);     // inf-safe
}

// compiler barrier: forces all previously-written loads to be issued before
// any following memory op / consumption is scheduled.  No runtime cost.
__device__ __forceinline__ void sched_fence(){ asm volatile("" ::: "memory"); }

// wave-0 parallel flag wait: lanes read flg[lane], flg[64+lane] (L0 flags,
// target tgt0) and flg[128+lane] (L1 flags, target tgt1).
__device__ __forceinline__ void waitflags2(const unsigned* f, unsigned tgt0,
                                           unsigned tgt1, int lane){
  for (;;){
    bool ok = (__hip_atomic_load(f + lane,       __ATOMIC_RELAXED, __HIP_MEMORY_SCOPE_AGENT) >= tgt0)
           && (__hip_atomic_load(f + 64 + lane,  __ATOMIC_RELAXED, __HIP_MEMORY_SCOPE_AGENT) >= tgt0)
           && (__hip_atomic_load(f + 128 + lane, __ATOMIC_RELAXED, __HIP_MEMORY_SCOPE_AGENT) >= tgt1);
    if (__all(ok)) return;
    __builtin_amdgcn_s_sleep(1);
  }
}

// acquire at agent scope: s_waitcnt + invalidate L1/L2 so subsequent normal
// cached loads refill fresh data from the coherence point.
__device__ __forceinline__ void acq_fence(){
  __builtin_amdgcn_fence(__ATOMIC_ACQUIRE, "agent");
}

// pack two pair-dword quads into hi-plane / lo-plane A fragments
__device__ __forceinline__ void frag_from_pairs(v4u p0, v4u p1, v8h& A, v8h& B){
  v4u ua, ub;
  ua[0] = __builtin_amdgcn_perm(p0[1], p0[0], 0x05040100u);
  ua[1] = __builtin_amdgcn_perm(p0[3], p0[2], 0x05040100u);
  ua[2] = __builtin_amdgcn_perm(p1[1], p1[0], 0x05040100u);
  ua[3] = __builtin_amdgcn_perm(p1[3], p1[2], 0x05040100u);
  ub[0] = __builtin_amdgcn_perm(p0[1], p0[0], 0x07060302u);
  ub[1] = __builtin_amdgcn_perm(p0[3], p0[2], 0x07060302u);
  ub[2] = __builtin_amdgcn_perm(p1[1], p1[0], 0x07060302u);
  ub[3] = __builtin_amdgcn_perm(p1[3], p1[2], 0x07060302u);
  A = as_h8(ua); B = as_h8(ub);
}

__device__ __forceinline__ void frag_from_floats(v4f f0, v4f f1, v8h& A, v8h& B){
  float v[8] = { f0[0], f0[1], f0[2], f0[3], f1[0], f1[1], f1[2], f1[3] };
  v4u ua, ub;
  #pragma unroll
  for (int d = 0; d < 4; ++d){
    unsigned p = pk2(v[2*d], v[2*d+1]);
    ua[d] = p;
    ub[d] = pk2(v[2*d] - lo16(p), v[2*d+1] - hi16(p));
  }
  A = as_h8(ua); B = as_h8(ub);
}

__global__ void __launch_bounds__(NTHR, 1)
lstm_mfma(const float* __restrict__ x, const unsigned* __restrict__ xp, int use_xp,
          const float* __restrict__ Wih0, const float* __restrict__ bih0,
          const float* __restrict__ Whh0, const float* __restrict__ bhh0,
          const float* __restrict__ Wih1, const float* __restrict__ bih1,
          const float* __restrict__ Whh1, const float* __restrict__ bhh1,
          unsigned* h1p, unsigned* h2p,
          unsigned* flg, float* out)
{
  __shared__ v4u wfbs[NKT * 64];       // 24 KB: lo-plane weight B-fragments

  const int tid   = threadIdx.x;
  const int wg    = blockIdx.x;
  const bool isL0 = wg < NWG0;
  const int lw    = isL0 ? wg : wg - NWG0;
  const int H     = isL0 ? H0 : H1;
  const int jbase = lw * 4;            // 4 h-cols per WG
  const int lane  = tid & 63;
  const int mt    = tid >> 6;          // wave id = m-tile (16 batches)
  const int n     = lane & 15;         // MFMA n-index / A row-in-tile
  const int quad  = lane >> 4;
  // n -> gate (n>>2 in {i,f,g,o}), h-col jbase + (n&3)
  const int gcol  = (n >> 2) * H + jbase + (n & 3);
  const int brow  = mt * 16 + n;       // batch row this lane loads for A

  // ---- prologue: gather weight B-fragments; hi-plane -> VGPRs, lo -> LDS ----
  v4u wfa[NKT];
  {
    const float* Wi = isL0 ? Wih0 : Wih1;
    const float* Wh = isL0 ? Whh0 : Whh1;
    const int Ki  = isL0 ? DIN : H0;
    const int ldw = 4 * H;
    #pragma unroll
    for (int kt = 0; kt < NKT; ++kt){
      const int ks = kt * 32 + quad * 8;
      float w[8];
      #pragma unroll
      for (int j = 0; j < 8; ++j){
        const int k = ks + j;
        w[j] = (k < Ki) ? Wi[(size_t)k * ldw + gcol]
                        : Wh[(size_t)(k - Ki) * ldw + gcol];
      }
      v4u ua, ub;
      #pragma unroll
      for (int d = 0; d < 4; ++d){
        const unsigned p = pk2(w[2*d], w[2*d+1]);
        ua[d] = p;
        ub[d] = pk2(w[2*d] - lo16(p), w[2*d+1] - hi16(p));
      }
      wfa[kt] = ua;
      if (mt == 0) wfbs[kt * 64 + lane] = ub;   // fragments identical across waves
    }
  }
  const float bsum = isL0 ? (bih0[gcol] + bhh0[gcol]) : (bih1[gcol] + bhh1[gcol]);

  float c0 = 0.f, c1 = 0.f, c2 = 0.f, c3 = 0.f;   // cell state (lanes n<4)
  __syncthreads();

  // iteration i: L0 computes h1(i) (for i < TT); L1 computes h2(i-1) (i >= 1)
  for (int i = 0; i <= TT; ++i){
    const bool act = isL0 ? (i < TT) : (i >= 1);
    const int t    = isL0 ? i : (i - 1);          // this WG's time index
    const int s_w  = ((unsigned)t) % 3u;          // h1 write slot (L0)
    const int s_r  = ((unsigned)(t + 2)) % 3u;    // h1(t-1) read slot (L0)
    const int s_c  = ((unsigned)t) % 3u;          // h1(t) read slot (L1)

    v4f acc1 = { bsum, bsum, bsum, bsum };
    v4f acc2 = { 0.f, 0.f, 0.f, 0.f };

    // ---- L0 x-part: no cross-WG dependency, runs before the wait.
    //      Forced register staging: all 16 loads in flight before compute. ----
    if (isL0 && act){
      if (use_xp){
        const unsigned* xr = xp + ((size_t)brow * TT + t) * DIN + quad * 8;
        v4u xP0[8], xP1[8];
        #pragma unroll
        for (int kt = 0; kt < 8; ++kt){
          xP0[kt] = *(const v4u*)(xr + kt * 32);
          xP1[kt] = *(const v4u*)(xr + kt * 32 + 4);
        }
        sched_fence();
        #pragma unroll
        for (int kt = 0; kt < 8; ++kt){
          v8h A, Ab; frag_from_pairs(xP0[kt], xP1[kt], A, Ab);
          v8h Wa = as_h8(wfa[kt]), Wb = as_h8(wfbs[kt * 64 + lane]);
          acc1 = mfma16(A,  Wa, acc1);
          acc2 = mfma16(A,  Wb, acc2);
          acc2 = mfma16(Ab, Wa, acc2);
        }
      } else {
        const float* xr = x + ((size_t)brow * TT + t) * DIN + quad * 8;
        v4f xF0[8], xF1[8];
        #pragma unroll
        for (int kt = 0; kt < 8; ++kt){
          xF0[kt] = *(const v4f*)(xr + kt * 32);
          xF1[kt] = *(const v4f*)(xr + kt * 32 + 4);
        }
        sched_fence();
        #pragma unroll
        for (int kt = 0; kt < 8; ++kt){
          v8h A, Ab; frag_from_floats(xF0[kt], xF1[kt], A, Ab);
          v8h Wa = as_h8(wfa[kt]), Wb = as_h8(wfbs[kt * 64 + lane]);
          acc1 = mfma16(A,  Wa, acc1);
          acc2 = mfma16(A,  Wb, acc2);
          acc2 = mfma16(Ab, Wa, acc2);
        }
      }
    }

    // ---- the per-iteration sync.  L0: own flags >= i, L1 flags >= i-1
    //      (slot-reuse guard only, one iteration of slack via 3-slot h1).
    //      L1: all flags >= i (true data dependency on h1(i-1), h2(i-2)). ----
    if (tid < 64){
      if (i >= 1){
        if (isL0) waitflags2(flg, (unsigned)i, (i >= 2) ? (unsigned)(i - 1) : 0u, lane);
        else      waitflags2(flg, (unsigned)i, (unsigned)i, lane);
      }
      acq_fence();          // unconditional: also guards graph-replay staleness
    }
    __syncthreads();

    if (act){
      if (isL0){
        // ---- h1(t-1) part, slot s_r: 32 loads forced in flight, then compute ----
        const unsigned* hr = h1p + (size_t)s_r * (BB * H0)
                                 + (size_t)brow * H0 + quad * 8;
        v4u hP0[16], hP1[16];
        #pragma unroll
        for (int kt = 0; kt < 16; ++kt){
          hP0[kt] = *(const v4u*)(hr + kt * 32);
          hP1[kt] = *(const v4u*)(hr + kt * 32 + 4);
        }
        sched_fence();
        #pragma unroll
        for (int kt = 0; kt < 16; ++kt){
          v8h A, Ab; frag_from_pairs(hP0[kt], hP1[kt], A, Ab);
          v8h Wa = as_h8(wfa[kt + 8]), Wb = as_h8(wfbs[(kt + 8) * 64 + lane]);
          acc1 = mfma16(A,  Wa, acc1);
          acc2 = mfma16(A,  Wb, acc2);
          acc2 = mfma16(Ab, Wa, acc2);
        }
      } else {
        // ---- L1: issue h2(t-1) loads (16) AND h1(t) loads (32) back-to-back,
        //      then compute h2 part, then h1 part ----
        const unsigned* h2r = h2p + (size_t)((t + 1) & 1) * (BB * H1)
                                  + (size_t)brow * H1 + quad * 8;
        const unsigned* hr  = h1p + (size_t)s_c * (BB * H0)
                                  + (size_t)brow * H0 + quad * 8;
        v4u aP0[8], aP1[8];
        #pragma unroll
        for (int kt = 0; kt < 8; ++kt){
          aP0[kt] = *(const v4u*)(h2r + kt * 32);
          aP1[kt] = *(const v4u*)(h2r + kt * 32 + 4);
        }
        v4u bP0[16], bP1[16];
        #pragma unroll
        for (int kt = 0; kt < 16; ++kt){
          bP0[kt] = *(const v4u*)(hr + kt * 32);
          bP1[kt] = *(const v4u*)(hr + kt * 32 + 4);
        }
        sched_fence();
        #pragma unroll
        for (int kt = 0; kt < 8; ++kt){
          v8h A, Ab; frag_from_pairs(aP0[kt], aP1[kt], A, Ab);
          v8h Wa = as_h8(wfa[kt + 16]), Wb = as_h8(wfbs[(kt + 16) * 64 + lane]);
          acc1 = mfma16(A,  Wa, acc1);
          acc2 = mfma16(A,  Wb, acc2);
          acc2 = mfma16(Ab, Wa, acc2);
        }
        #pragma unroll
        for (int kt = 0; kt < 16; ++kt){
          v8h A, Ab; frag_from_pairs(bP0[kt], bP1[kt], A, Ab);
          v8h Wa = as_h8(wfa[kt]), Wb = as_h8(wfbs[kt * 64 + lane]);
          acc1 = mfma16(A,  Wa, acc1);
          acc2 = mfma16(A,  Wb, acc2);
          acc2 = mfma16(Ab, Wa, acc2);
        }
      }

      // ---- elementwise LSTM: gather (i,f,g,o) per (b, h-col) via shfl_xor ----
      v4f gv = acc1 + acc2;
      float pv0 = __shfl_xor(gv[0], 4), pv1 = __shfl_xor(gv[1], 4),
            pv2 = __shfl_xor(gv[2], 4), pv3 = __shfl_xor(gv[3], 4);
      float qv0 = __shfl_xor(gv[0], 8), qv1 = __shfl_xor(gv[1], 8),
            qv2 = __shfl_xor(gv[2], 8), qv3 = __shfl_xor(gv[3], 8);
      float sv0 = __shfl_xor(pv0, 8), sv1 = __shfl_xor(pv1, 8),
            sv2 = __shfl_xor(pv2, 8), sv3 = __shfl_xor(pv3, 8);

      if (n < 4){
        // lane n<4: i = gv, f = pv, g = qv, o = sv ; rows b = mt*16 + quad*4 + r
        float iv[4] = { gv[0], gv[1], gv[2], gv[3] };
        float fv[4] = { pv0, pv1, pv2, pv3 };
        float gg[4] = { qv0, qv1, qv2, qv3 };
        float ov[4] = { sv0, sv1, sv2, sv3 };
        float cc[4] = { c0, c1, c2, c3 };
        const int col = jbase + n;
        #pragma unroll
        for (int r = 0; r < 4; ++r){
          float cn = sigf(fv[r]) * cc[r] + sigf(iv[r]) * tanhf_(gg[r]);
          float hn = sigf(ov[r]) * tanhf_(cn);
          cc[r] = cn;
          const int b = mt * 16 + quad * 4 + r;
          unsigned pa = pk2(hn, 0.f);
          unsigned pd = pk2(hn, hn - lo16(pa));
          if (isL0){
            __hip_atomic_store(h1p + (size_t)s_w * (BB * H0) + (size_t)b * H0 + col,
                               pd, __ATOMIC_RELAXED, __HIP_MEMORY_SCOPE_AGENT);
          } else {
            __hip_atomic_store(h2p + (size_t)(t & 1) * (BB * H1) + (size_t)b * H1 + col,
                               pd, __ATOMIC_RELAXED, __HIP_MEMORY_SCOPE_AGENT);
            // write-through so per-step L2 invalidates never see a dirty line
            __hip_atomic_store(out + ((size_t)b * TT + t) * H1 + col, hn,
                               __ATOMIC_RELAXED, __HIP_MEMORY_SCOPE_AGENT);
          }
        }
        c0 = cc[0]; c1 = cc[1]; c2 = cc[2]; c3 = cc[3];
      }
    }

    // ---- publish: barrier drains vmcnt (write-through stores are at the
    // coherence point once retired) -> per-WG relaxed flag store suffices ----
    __syncthreads();
    if (tid == 0){
      __hip_atomic_store(flg + wg, (unsigned)(i + 1),
                         __ATOMIC_RELAXED, __HIP_MEMORY_SCOPE_AGENT);
    }
  }
}

__global__ void init_ws(unsigned* ws, int nz){
  int i = blockIdx.x * blockDim.x + threadIdx.x;
  if (i < nz)
    __hip_atomic_store(ws + i, 0u, __ATOMIC_RELAXED, __HIP_MEMORY_SCOPE_AGENT);
}

__global__ void conv_x(const float4* __restrict__ x4,
                       unsigned long long* __restrict__ xp2, int n4){
  int i = blockIdx.x * blockDim.x + threadIdx.x;
  if (i >= n4) return;
  float4 f = x4[i];
  float v[4] = { f.x, f.y, f.z, f.w };
  unsigned o[4];
  #pragma unroll
  for (int d = 0; d < 4; ++d){
    unsigned p = pk2(v[d], 0.f);
    o[d] = pk2(v[d], v[d] - lo16(p));
  }
  unsigned long long lo = (unsigned long long)o[0] | ((unsigned long long)o[1] << 32);
  unsigned long long hi = (unsigned long long)o[2] | ((unsigned long long)o[3] << 32);
  // write-through: no dirty L2 lines to be lost by lstm_mfma's invalidates
  __hip_atomic_store(xp2 + 2 * i + 0, lo, __ATOMIC_RELAXED, __HIP_MEMORY_SCOPE_AGENT);
  __hip_atomic_store(xp2 + 2 * i + 1, hi, __ATOMIC_RELAXED, __HIP_MEMORY_SCOPE_AGENT);
}

extern "C" void kernel_launch(void* const* d_in, const int* in_sizes, int n_in,
                              void* d_out, int out_size, void* d_ws, size_t ws_size,
                              hipStream_t stream) {
  const float* x    = (const float*)d_in[0];
  const float* Wih0 = (const float*)d_in[1];
  const float* bih0 = (const float*)d_in[2];
  const float* Whh0 = (const float*)d_in[3];
  const float* bhh0 = (const float*)d_in[4];
  const float* Wih1 = (const float*)d_in[5];
  const float* bih1 = (const float*)d_in[6];
  const float* Whh1 = (const float*)d_in[7];
  const float* bhh1 = (const float*)d_in[8];
  float* outp = (float*)d_out;

  unsigned* ws   = (unsigned*)d_ws;
  unsigned* h1p  = ws;                       // 3*64*512  = 98304 dwords (3 slots)
  unsigned* h2p  = h1p + 3 * BB * H0;        // 2*64*256  = 32768
  unsigned* flg  = h2p + 2 * BB * H1;        // region sized 2*TT dwords (uses 192)
  unsigned* xp   = flg + 2 * TT;             // optional: B*T*DIN pair dwords
  const int nz = 3 * BB * H0 + 2 * BB * H1 + 2 * TT;   // dwords to zero

  const size_t need_xp = ((size_t)nz + (size_t)BB * TT * DIN) * 4;
  int use_xp = (ws_size >= need_xp) ? 1 : 0;

  init_ws<<<dim3((nz + 255) / 256), dim3(256), 0, stream>>>(ws, nz);
  if (use_xp){
    const int n4 = BB * TT * DIN / 4;
    conv_x<<<dim3((n4 + 255) / 256), dim3(256), 0, stream>>>(
        (const float4*)x, (unsigned long long*)xp, n4);
  }

  lstm_mfma<<<dim3(NWG), dim3(NTHR), 0, stream>>>(
      x, xp, use_xp,
      Wih0, bih0, Whh0, bhh0,
      Wih1, bih1, Whh1, bhh1,
      h1p, h2p, flg, outp);
}

// Round 5
// 9272.173 us; speedup vs baseline: 1.0014x; 1.0014x over previous
//
#include <hip/hip_runtime.h>

// ---------------------------------------------------------------------------
// V8: persistent MFMA LSTM — TRUE load batching via sched_barrier(0).
//  Protocol (verified V4-V7): release = write-through h stores (sc0 sc1) ->
//  __syncthreads vmcnt drain -> per-WG relaxed flag store.  acquire = wave-0
//  polls flags -> agent acquire fence (L1/L2 inv) -> __syncthreads -> normal
//  cached loads.  Skewed schedule (V5): iter i = L0:h1(i), L1:h2(i-1).
//  h1 triple-buffered (V7): L0's slot-reuse guard = L1 flags >= i-1.
//
//  NEW vs V7: the load/consume separation uses
//      __builtin_amdgcn_sched_barrier(0)
//  instead of asm volatile("" ::: "memory").  The memory clobber only orders
//  MEMORY ops; the register-only frag/MFMA consumers were hoisted up between
//  the loads (VGPR_Count=180 proved it), re-serializing the refill into
//  dependent ~900ns MALL-latency chains.  sched_barrier(0) blocks ALL
//  instruction movement, forcing every load of a phase in flight before any
//  consumption -> refill ~= 1 latency + transfer.  Expected VGPR ~300+.
// ---------------------------------------------------------------------------

constexpr int BB   = 64;
constexpr int TT   = 1024;
constexpr int DIN  = 256;
constexpr int H0   = 512;
constexpr int H1   = 256;
constexpr int NWG0 = 128;
constexpr int NWG1 = 64;
constexpr int NWG  = NWG0 + NWG1;
constexpr int NTHR = 256;
constexpr int NKT  = 24;       // K = 768 = 24 tiles of 32

typedef _Float16 v8h __attribute__((ext_vector_type(8)));
typedef __fp16   v2p __attribute__((ext_vector_type(2)));   // cvt_pkrtz result type
typedef float    v4f __attribute__((ext_vector_type(4)));
typedef unsigned int v4u __attribute__((ext_vector_type(4)));

union U1 { unsigned u; v2p h; };
union U4 { v4u u; v8h h; };

__device__ __forceinline__ unsigned pk2(float a, float b){
  U1 c; c.h = __builtin_amdgcn_cvt_pkrtz(a, b); return c.u;
}
__device__ __forceinline__ float lo16(unsigned u){ U1 c; c.u = u; return (float)c.h[0]; }
__device__ __forceinline__ float hi16(unsigned u){ U1 c; c.u = u; return (float)c.h[1]; }
__device__ __forceinline__ v8h as_h8(v4u u){ U4 c; c.u = u; return c.h; }

__device__ __forceinline__ v4f mfma16(v8h a, v8h b, v4f c){
  return __builtin_amdgcn_mfma_f32_16x16x32_f16(a, b, c, 0, 0, 0);
}

__device__ __forceinline__ float sigf(float v){ return 1.0f / (1.0f + __expf(-v)); }
__device__ __forceinline__ float tanhf_(float v){
  float e = __expf(2.0f * v);
  return 1.0f - 2.0f / (e + 1.0f);     // inf-safe
}

// scheduler fence: blocks movement of ALL instruction classes across this
// point (VALU/MFMA included — unlike an asm "memory" clobber, which lets
// register-only consumers hoist between the loads; see V7 post-mortem).
__device__ __forceinline__ void sched_cut(){ __builtin_amdgcn_sched_barrier(0); }

// wave-0 parallel flag wait: lanes read flg[lane], flg[64+lane] (L0 flags,
// target tgt0) and flg[128+lane] (L1 flags, target tgt1).
__device__ __forceinline__ void waitflags2(const unsigned* f, unsigned tgt0,
                                           unsigned tgt1, int lane){
  for (;;){
    bool ok = (__hip_atomic_load(f + lane,       __ATOMIC_RELAXED, __HIP_MEMORY_SCOPE_AGENT) >= tgt0)
           && (__hip_atomic_load(f + 64 + lane,  __ATOMIC_RELAXED, __HIP_MEMORY_SCOPE_AGENT) >= tgt0)
           && (__hip_atomic_load(f + 128 + lane, __ATOMIC_RELAXED, __HIP_MEMORY_SCOPE_AGENT) >= tgt1);
    if (__all(ok)) return;
    __builtin_amdgcn_s_sleep(1);
  }
}

// acquire at agent scope: s_waitcnt + invalidate L1/L2 so subsequent normal
// cached loads refill fresh data from the coherence point.
__device__ __forceinline__ void acq_fence(){
  __builtin_amdgcn_fence(__ATOMIC_ACQUIRE, "agent");
}

// pack two pair-dword quads into hi-plane / lo-plane A fragments
__device__ __forceinline__ void frag_from_pairs(v4u p0, v4u p1, v8h& A, v8h& B){
  v4u ua, ub;
  ua[0] = __builtin_amdgcn_perm(p0[1], p0[0], 0x05040100u);
  ua[1] = __builtin_amdgcn_perm(p0[3], p0[2], 0x05040100u);
  ua[2] = __builtin_amdgcn_perm(p1[1], p1[0], 0x05040100u);
  ua[3] = __builtin_amdgcn_perm(p1[3], p1[2], 0x05040100u);
  ub[0] = __builtin_amdgcn_perm(p0[1], p0[0], 0x07060302u);
  ub[1] = __builtin_amdgcn_perm(p0[3], p0[2], 0x07060302u);
  ub[2] = __builtin_amdgcn_perm(p1[1], p1[0], 0x07060302u);
  ub[3] = __builtin_amdgcn_perm(p1[3], p1[2], 0x07060302u);
  A = as_h8(ua); B = as_h8(ub);
}

__device__ __forceinline__ void frag_from_floats(v4f f0, v4f f1, v8h& A, v8h& B){
  float v[8] = { f0[0], f0[1], f0[2], f0[3], f1[0], f1[1], f1[2], f1[3] };
  v4u ua, ub;
  #pragma unroll
  for (int d = 0; d < 4; ++d){
    unsigned p = pk2(v[2*d], v[2*d+1]);
    ua[d] = p;
    ub[d] = pk2(v[2*d] - lo16(p), v[2*d+1] - hi16(p));
  }
  A = as_h8(ua); B = as_h8(ub);
}

__global__ void __launch_bounds__(NTHR, 1)
lstm_mfma(const float* __restrict__ x, const unsigned* __restrict__ xp, int use_xp,
          const float* __restrict__ Wih0, const float* __restrict__ bih0,
          const float* __restrict__ Whh0, const float* __restrict__ bhh0,
          const float* __restrict__ Wih1, const float* __restrict__ bih1,
          const float* __restrict__ Whh1, const float* __restrict__ bhh1,
          unsigned* h1p, unsigned* h2p,
          unsigned* flg, float* out)
{
  __shared__ v4u wfbs[NKT * 64];       // 24 KB: lo-plane weight B-fragments

  const int tid   = threadIdx.x;
  const int wg    = blockIdx.x;
  const bool isL0 = wg < NWG0;
  const int lw    = isL0 ? wg : wg - NWG0;
  const int H     = isL0 ? H0 : H1;
  const int jbase = lw * 4;            // 4 h-cols per WG
  const int lane  = tid & 63;
  const int mt    = tid >> 6;          // wave id = m-tile (16 batches)
  const int n     = lane & 15;         // MFMA n-index / A row-in-tile
  const int quad  = lane >> 4;
  // n -> gate (n>>2 in {i,f,g,o}), h-col jbase + (n&3)
  const int gcol  = (n >> 2) * H + jbase + (n & 3);
  const int brow  = mt * 16 + n;       // batch row this lane loads for A

  // ---- prologue: gather weight B-fragments; hi-plane -> VGPRs, lo -> LDS ----
  v4u wfa[NKT];
  {
    const float* Wi = isL0 ? Wih0 : Wih1;
    const float* Wh = isL0 ? Whh0 : Whh1;
    const int Ki  = isL0 ? DIN : H0;
    const int ldw = 4 * H;
    #pragma unroll
    for (int kt = 0; kt < NKT; ++kt){
      const int ks = kt * 32 + quad * 8;
      float w[8];
      #pragma unroll
      for (int j = 0; j < 8; ++j){
        const int k = ks + j;
        w[j] = (k < Ki) ? Wi[(size_t)k * ldw + gcol]
                        : Wh[(size_t)(k - Ki) * ldw + gcol];
      }
      v4u ua, ub;
      #pragma unroll
      for (int d = 0; d < 4; ++d){
        const unsigned p = pk2(w[2*d], w[2*d+1]);
        ua[d] = p;
        ub[d] = pk2(w[2*d] - lo16(p), w[2*d+1] - hi16(p));
      }
      wfa[kt] = ua;
      if (mt == 0) wfbs[kt * 64 + lane] = ub;   // fragments identical across waves
    }
  }
  const float bsum = isL0 ? (bih0[gcol] + bhh0[gcol]) : (bih1[gcol] + bhh1[gcol]);

  float c0 = 0.f, c1 = 0.f, c2 = 0.f, c3 = 0.f;   // cell state (lanes n<4)
  __syncthreads();

  // iteration i: L0 computes h1(i) (for i < TT); L1 computes h2(i-1) (i >= 1)
  for (int i = 0; i <= TT; ++i){
    const bool act = isL0 ? (i < TT) : (i >= 1);
    const int t    = isL0 ? i : (i - 1);          // this WG's time index
    const int s_w  = ((unsigned)t) % 3u;          // h1 write slot (L0)
    const int s_r  = ((unsigned)(t + 2)) % 3u;    // h1(t-1) read slot (L0)
    const int s_c  = ((unsigned)t) % 3u;          // h1(t) read slot (L1)

    v4f acc1 = { bsum, bsum, bsum, bsum };
    v4f acc2 = { 0.f, 0.f, 0.f, 0.f };

    // ---- L0 x-part: no cross-WG dependency, runs before the wait.
    //      All 16 loads forced in flight (sched_barrier) before compute. ----
    if (isL0 && act){
      if (use_xp){
        const unsigned* xr = xp + ((size_t)brow * TT + t) * DIN + quad * 8;
        v4u xP0[8], xP1[8];
        #pragma unroll
        for (int kt = 0; kt < 8; ++kt){
          xP0[kt] = *(const v4u*)(xr + kt * 32);
          xP1[kt] = *(const v4u*)(xr + kt * 32 + 4);
        }
        sched_cut();
        #pragma unroll
        for (int kt = 0; kt < 8; ++kt){
          v8h A, Ab; frag_from_pairs(xP0[kt], xP1[kt], A, Ab);
          v8h Wa = as_h8(wfa[kt]), Wb = as_h8(wfbs[kt * 64 + lane]);
          acc1 = mfma16(A,  Wa, acc1);
          acc2 = mfma16(A,  Wb, acc2);
          acc2 = mfma16(Ab, Wa, acc2);
        }
      } else {
        const float* xr = x + ((size_t)brow * TT + t) * DIN + quad * 8;
        v4f xF0[8], xF1[8];
        #pragma unroll
        for (int kt = 0; kt < 8; ++kt){
          xF0[kt] = *(const v4f*)(xr + kt * 32);
          xF1[kt] = *(const v4f*)(xr + kt * 32 + 4);
        }
        sched_cut();
        #pragma unroll
        for (int kt = 0; kt < 8; ++kt){
          v8h A, Ab; frag_from_floats(xF0[kt], xF1[kt], A, Ab);
          v8h Wa = as_h8(wfa[kt]), Wb = as_h8(wfbs[kt * 64 + lane]);
          acc1 = mfma16(A,  Wa, acc1);
          acc2 = mfma16(A,  Wb, acc2);
          acc2 = mfma16(Ab, Wa, acc2);
        }
      }
    }

    // ---- the per-iteration sync.  L0: own flags >= i, L1 flags >= i-1
    //      (slot-reuse guard only, one iteration of slack via 3-slot h1).
    //      L1: all flags >= i (true data dependency on h1(i-1), h2(i-2)). ----
    if (tid < 64){
      if (i >= 1){
        if (isL0) waitflags2(flg, (unsigned)i, (i >= 2) ? (unsigned)(i - 1) : 0u, lane);
        else      waitflags2(flg, (unsigned)i, (unsigned)i, lane);
      }
      acq_fence();          // unconditional: also guards graph-replay staleness
    }
    __syncthreads();

    if (act){
      if (isL0){
        // ---- h1(t-1) part, slot s_r: 32 loads forced in flight, then compute ----
        const unsigned* hr = h1p + (size_t)s_r * (BB * H0)
                                 + (size_t)brow * H0 + quad * 8;
        v4u hP0[16], hP1[16];
        #pragma unroll
        for (int kt = 0; kt < 16; ++kt){
          hP0[kt] = *(const v4u*)(hr + kt * 32);
          hP1[kt] = *(const v4u*)(hr + kt * 32 + 4);
        }
        sched_cut();
        #pragma unroll
        for (int kt = 0; kt < 16; ++kt){
          v8h A, Ab; frag_from_pairs(hP0[kt], hP1[kt], A, Ab);
          v8h Wa = as_h8(wfa[kt + 8]), Wb = as_h8(wfbs[(kt + 8) * 64 + lane]);
          acc1 = mfma16(A,  Wa, acc1);
          acc2 = mfma16(A,  Wb, acc2);
          acc2 = mfma16(Ab, Wa, acc2);
        }
      } else {
        // ---- L1: issue h2(t-1) loads (16) AND h1(t) loads (32) back-to-back,
        //      scheduler-fenced, then compute h2 part, then h1 part ----
        const unsigned* h2r = h2p + (size_t)((t + 1) & 1) * (BB * H1)
                                  + (size_t)brow * H1 + quad * 8;
        const unsigned* hr  = h1p + (size_t)s_c * (BB * H0)
                                  + (size_t)brow * H0 + quad * 8;
        v4u aP0[8], aP1[8];
        #pragma unroll
        for (int kt = 0; kt < 8; ++kt){
          aP0[kt] = *(const v4u*)(h2r + kt * 32);
          aP1[kt] = *(const v4u*)(h2r + kt * 32 + 4);
        }
        v4u bP0[16], bP1[16];
        #pragma unroll
        for (int kt = 0; kt < 16; ++kt){
          bP0[kt] = *(const v4u*)(hr + kt * 32);
          bP1[kt] = *(const v4u*)(hr + kt * 32 + 4);
        }
        sched_cut();
        #pragma unroll
        for (int kt = 0; kt < 8; ++kt){
          v8h A, Ab; frag_from_pairs(aP0[kt], aP1[kt], A, Ab);
          v8h Wa = as_h8(wfa[kt + 16]), Wb = as_h8(wfbs[(kt + 16) * 64 + lane]);
          acc1 = mfma16(A,  Wa, acc1);
          acc2 = mfma16(A,  Wb, acc2);
          acc2 = mfma16(Ab, Wa, acc2);
        }
        #pragma unroll
        for (int kt = 0; kt < 16; ++kt){
          v8h A, Ab; frag_from_pairs(bP0[kt], bP1[kt], A, Ab);
          v8h Wa = as_h8(wfa[kt]), Wb = as_h8(wfbs[kt * 64 + lane]);
          acc1 = mfma16(A,  Wa, acc1);
          acc2 = mfma16(A,  Wb, acc2);
          acc2 = mfma16(Ab, Wa, acc2);
        }
      }

      // ---- elementwise LSTM: gather (i,f,g,o) per (b, h-col) via shfl_xor ----
      v4f gv = acc1 + acc2;
      float pv0 = __shfl_xor(gv[0], 4), pv1 = __shfl_xor(gv[1], 4),
            pv2 = __shfl_xor(gv[2], 4), pv3 = __shfl_xor(gv[3], 4);
      float qv0 = __shfl_xor(gv[0], 8), qv1 = __shfl_xor(gv[1], 8),
            qv2 = __shfl_xor(gv[2], 8), qv3 = __shfl_xor(gv[3], 8);
      float sv0 = __shfl_xor(pv0, 8), sv1 = __shfl_xor(pv1, 8),
            sv2 = __shfl_xor(pv2, 8), sv3 = __shfl_xor(pv3, 8);

      if (n < 4){
        // lane n<4: i = gv, f = pv, g = qv, o = sv ; rows b = mt*16 + quad*4 + r
        float iv[4] = { gv[0], gv[1], gv[2], gv[3] };
        float fv[4] = { pv0, pv1, pv2, pv3 };
        float gg[4] = { qv0, qv1, qv2, qv3 };
        float ov[4] = { sv0, sv1, sv2, sv3 };
        float cc[4] = { c0, c1, c2, c3 };
        const int col = jbase + n;
        #pragma unroll
        for (int r = 0; r < 4; ++r){
          float cn = sigf(fv[r]) * cc[r] + sigf(iv[r]) * tanhf_(gg[r]);
          float hn = sigf(ov[r]) * tanhf_(cn);
          cc[r] = cn;
          const int b = mt * 16 + quad * 4 + r;
          unsigned pa = pk2(hn, 0.f);
          unsigned pd = pk2(hn, hn - lo16(pa));
          if (isL0){
            __hip_atomic_store(h1p + (size_t)s_w * (BB * H0) + (size_t)b * H0 + col,
                               pd, __ATOMIC_RELAXED, __HIP_MEMORY_SCOPE_AGENT);
          } else {
            __hip_atomic_store(h2p + (size_t)(t & 1) * (BB * H1) + (size_t)b * H1 + col,
                               pd, __ATOMIC_RELAXED, __HIP_MEMORY_SCOPE_AGENT);
            // write-through so per-step L2 invalidates never see a dirty line
            __hip_atomic_store(out + ((size_t)b * TT + t) * H1 + col, hn,
                               __ATOMIC_RELAXED, __HIP_MEMORY_SCOPE_AGENT);
          }
        }
        c0 = cc[0]; c1 = cc[1]; c2 = cc[2]; c3 = cc[3];
      }
    }

    // ---- publish: barrier drains vmcnt (write-through stores are at the
    // coherence point once retired) -> per-WG relaxed flag store suffices ----
    __syncthreads();
    if (tid == 0){
      __hip_atomic_store(flg + wg, (unsigned)(i + 1),
                         __ATOMIC_RELAXED, __HIP_MEMORY_SCOPE_AGENT);
    }
  }
}

__global__ void init_ws(unsigned* ws, int nz){
  int i = blockIdx.x * blockDim.x + threadIdx.x;
  if (i < nz)
    __hip_atomic_store(ws + i, 0u, __ATOMIC_RELAXED, __HIP_MEMORY_SCOPE_AGENT);
}

__global__ void conv_x(const float4* __restrict__ x4,
                       unsigned long long* __restrict__ xp2, int n4){
  int i = blockIdx.x * blockDim.x + threadIdx.x;
  if (i >= n4) return;
  float4 f = x4[i];
  float v[4] = { f.x, f.y, f.z, f.w };
  unsigned o[4];
  #pragma unroll
  for (int d = 0; d < 4; ++d){
    unsigned p = pk2(v[d], 0.f);
    o[d] = pk2(v[d], v[d] - lo16(p));
  }
  unsigned long long lo = (unsigned long long)o[0] | ((unsigned long long)o[1] << 32);
  unsigned long long hi = (unsigned long long)o[2] | ((unsigned long long)o[3] << 32);
  // write-through: no dirty L2 lines to be lost by lstm_mfma's invalidates
  __hip_atomic_store(xp2 + 2 * i + 0, lo, __ATOMIC_RELAXED, __HIP_MEMORY_SCOPE_AGENT);
  __hip_atomic_store(xp2 + 2 * i + 1, hi, __ATOMIC_RELAXED, __HIP_MEMORY_SCOPE_AGENT);
}

extern "C" void kernel_launch(void* const* d_in, const int* in_sizes, int n_in,
                              void* d_out, int out_size, void* d_ws, size_t ws_size,
                              hipStream_t stream) {
  const float* x    = (const float*)d_in[0];
  const float* Wih0 = (const float*)d_in[1];
  const float* bih0 = (const float*)d_in[2];
  const float* Whh0 = (const float*)d_in[3];
  const float* bhh0 = (const float*)d_in[4];
  const float* Wih1 = (const float*)d_in[5];
  const float* bih1 = (const float*)d_in[6];
  const float* Whh1 = (const float*)d_in[7];
  const float* bhh1 = (const float*)d_in[8];
  float* outp = (float*)d_out;

  unsigned* ws   = (unsigned*)d_ws;
  unsigned* h1p  = ws;                       // 3*64*512  = 98304 dwords (3 slots)
  unsigned* h2p  = h1p + 3 * BB * H0;        // 2*64*256  = 32768
  unsigned* flg  = h2p + 2 * BB * H1;        // region sized 2*TT dwords (uses 192)
  unsigned* xp   = flg + 2 * TT;             // optional: B*T*DIN pair dwords
  const int nz = 3 * BB * H0 + 2 * BB * H1 + 2 * TT;   // dwords to zero

  const size_t need_xp = ((size_t)nz + (size_t)BB * TT * DIN) * 4;
  int use_xp = (ws_size >= need_xp) ? 1 : 0;

  init_ws<<<dim3((nz + 255) / 256), dim3(256), 0, stream>>>(ws, nz);
  if (use_xp){
    const int n4 = BB * TT * DIN / 4;
    conv_x<<<dim3((n4 + 255) / 256), dim3(256), 0, stream>>>(
        (const float4*)x, (unsigned long long*)xp, n4);
  }

  lstm_mfma<<<dim3(NWG), dim3(NTHR), 0, stream>>>(
      x, xp, use_xp,
      Wih0, bih0, Whh0, bhh0,
      Wih1, bih1, Whh1, bhh1,
      h1p, h2p, flg, outp);
}